// Round 4
// baseline (578.217 us; speedup 1.0000x reference)
//
#include <hip/hip_runtime.h>
#include <stdint.h>

// Dtype policy (confirmed round 3): device inputs and output are float32.
// Internally bf16 MFMA with f32 accumulate; residual adds read original f32.
// Masked-query rows: reference's -1e9 bias ABSORBS scores in f32 (ulp(1e9)=64),
// so softmax is exactly uniform over all keys -> emulate with scores=0.

typedef unsigned short u16;
typedef __attribute__((ext_vector_type(4))) float f32x4;
typedef __attribute__((ext_vector_type(8))) short short8;
typedef __attribute__((ext_vector_type(4))) short s16x4;
typedef __attribute__((ext_vector_type(8))) __bf16 bf16x8;

__device__ __forceinline__ float b2f(u16 u){
  union { unsigned int i; float f; } v; v.i = ((unsigned int)u) << 16; return v.f;
}
__device__ __forceinline__ u16 f2b(float f){
  union { float f; unsigned int i; } v; v.f = f;
  unsigned int u = v.i;
  u = u + 0x7FFFu + ((u >> 16) & 1u);   // RNE
  return (u16)(u >> 16);
}
__device__ __forceinline__ f32x4 mfma16(short8 a, short8 b, f32x4 c){
  return __builtin_amdgcn_mfma_f32_16x16x32_bf16(
      __builtin_bit_cast(bf16x8, a), __builtin_bit_cast(bf16x8, b), c, 0, 0, 0);
}
__device__ __forceinline__ void gload16(const void* g, void* l){
  void* gnc = const_cast<void*>(g);
  __builtin_amdgcn_global_load_lds((__attribute__((address_space(1))) void*)gnc,
                                   (__attribute__((address_space(3))) void*)l, 16, 0, 0);
}

// ---------------- f32 -> bf16 weight conversion -----------------------------
__global__ __launch_bounds__(256) void cvt_k(const float* __restrict__ in,
                                             u16* __restrict__ out, int n4)
{
  int i = blockIdx.x*256 + threadIdx.x;
  if (i < n4){
    float4 v = *(const float4*)(in + (size_t)i*4);
    s16x4 o; o[0]=(short)f2b(v.x); o[1]=(short)f2b(v.y);
    o[2]=(short)f2b(v.z); o[3]=(short)f2b(v.w);
    *(s16x4*)(out + (size_t)i*4) = o;
  }
}

// ---------------- adaLN modulation: mod[b][6*768] = c @ Wada^T + bada --------
__global__ __launch_bounds__(256) void mod_k(const float* __restrict__ c,
    const float* __restrict__ Wada, const float* __restrict__ bada, float* __restrict__ modb)
{
  int o = blockIdx.x*4 + (threadIdx.x >> 6);   // 0..9215
  int l = threadIdx.x & 63;
  int b = o / 4608, j = o - b*4608;
  const float* cp = c + b*768;
  const float* wp = Wada + (size_t)j*768;
  float s = 0.f;
  for (int k = l; k < 768; k += 64) s += cp[k] * wp[k];
  #pragma unroll
  for (int d=1; d<64; d<<=1) s += __shfl_xor(s, d);
  if (l == 0) modb[o] = s + bada[j];
}

// ---------------- LayerNorm (no affine) * w * (1+scale) + shift -> bf16 -----
__global__ __launch_bounds__(256) void ln_mod_k(const float* __restrict__ xin,
    u16* __restrict__ out, const float* __restrict__ lnw, const float* __restrict__ modb,
    int shift_c, int scale_c)
{
  int row = blockIdx.x;             // 0..8191 (b*4096+s)
  int b = row >> 12;
  const float* xp = xin + (size_t)row*768;
  int t = threadIdx.x;
  float v[3]; float s = 0.f, s2 = 0.f;
  #pragma unroll
  for (int i=0;i<3;i++){ float f = xp[t + i*256]; v[i] = f; s += f; s2 += f*f; }
  #pragma unroll
  for (int d=1; d<64; d<<=1){ s += __shfl_xor(s, d); s2 += __shfl_xor(s2, d); }
  __shared__ float rs_[4], rs2_[4];
  int w = t >> 6;
  if ((t & 63) == 0){ rs_[w] = s; rs2_[w] = s2; }
  __syncthreads();
  s  = rs_[0]+rs_[1]+rs_[2]+rs_[3];
  s2 = rs2_[0]+rs2_[1]+rs2_[2]+rs2_[3];
  float mu  = s * (1.f/768.f);
  float var = fmaxf(s2 * (1.f/768.f) - mu*mu, 0.f);
  float rstd = rsqrtf(var + 1e-5f);
  const float* scp = modb + b*4608 + scale_c*768;
  const float* shp = modb + b*4608 + shift_c*768;
  #pragma unroll
  for (int i=0;i<3;i++){
    int d = t + i*256;
    float f = (v[i]-mu)*rstd*lnw[d];
    f = f*(1.f + scp[d]) + shp[d];
    out[(size_t)row*768 + d] = f2b(f);
  }
}

// ---------------- 128x128 BK=64 GEMM, C = A[M,K] @ Bt[N,K]^T, fused epilogues
// EPI 0: C(bf16)=acc (qkv).     1: C(f32) = x + gate_msa*acc (x1).
// EPI 2: C(bf16)=gelu(acc+b1).  3: C(f32) = x1 + gate_mlp*(acc+b2).
template<int EPI>
__global__ __launch_bounds__(256) void gemm_k(
    const u16* __restrict__ A, const u16* __restrict__ Bt, void* __restrict__ Cv,
    int M, int N, int K,
    const float* __restrict__ addend, const float* __restrict__ modb,
    const float* __restrict__ bias)
{
  __shared__ __align__(16) u16 As[128*64];
  __shared__ __align__(16) u16 Bs[128*64];
  const int bm = blockIdx.x, bn = blockIdx.y;
  const int tid = threadIdx.x;
  const int w = tid >> 6, l = tid & 63;
  const int wr = w >> 1, wc = w & 1;
  const int l15 = l & 15, lg = l >> 4;
  f32x4 acc[4][4] = {};

  for (int k0 = 0; k0 < K; k0 += 64){
    // stage: LDS slot (row, ch) holds global chunk (ch ^ (row&7))  [rule 21]
    #pragma unroll
    for (int i=0;i<4;i++){
      int e = i*256 + tid;
      int r = e >> 3, ch = e & 7;
      int sc = ch ^ (r & 7);
      gload16(A  + (size_t)(bm*128 + r)*K + k0 + sc*8, &As[e*8]);
      gload16(Bt + (size_t)(bn*128 + r)*K + k0 + sc*8, &Bs[e*8]);
    }
    __syncthreads();
    #pragma unroll
    for (int kk=0;kk<2;kk++){
      short8 af[4], bfv[4];
      #pragma unroll
      for (int i=0;i<4;i++){
        int ra = wr*64 + i*16 + l15;
        af[i]  = *(const short8*)&As[ra*64 + (((kk*4)+lg) ^ (ra&7))*8];
        int rb = wc*64 + i*16 + l15;
        bfv[i] = *(const short8*)&Bs[rb*64 + (((kk*4)+lg) ^ (rb&7))*8];
      }
      #pragma unroll
      for (int m=0;m<4;m++)
        #pragma unroll
        for (int n=0;n<4;n++)
          acc[m][n] = mfma16(af[m], bfv[n], acc[m][n]);
    }
    __syncthreads();
  }

  #pragma unroll
  for (int m=0;m<4;m++){
    int row0 = bm*128 + wr*64 + m*16 + lg*4;
    #pragma unroll
    for (int n=0;n<4;n++){
      int col = bn*128 + wc*64 + n*16 + l15;
      #pragma unroll
      for (int r=0;r<4;r++){
        int row = row0 + r;
        size_t idx = (size_t)row*N + col;
        float v = acc[m][n][r];
        if constexpr (EPI == 0){
          ((u16*)Cv)[idx] = f2b(v);
        } else if constexpr (EPI == 1){
          float g = modb[(row>>12)*4608 + 2*768 + col];   // gate_msa
          ((float*)Cv)[idx] = addend[idx] + g*v;
        } else if constexpr (EPI == 2){
          float u = v + bias[col];
          float t0 = 0.7978845608028654f*(u + 0.044715f*u*u*u);
          ((u16*)Cv)[idx] = f2b(0.5f*u*(1.0f + tanhf(t0)));
        } else {
          float g = modb[(row>>12)*4608 + 5*768 + col];   // gate_mlp
          float u = v + bias[col];
          ((float*)Cv)[idx] = addend[idx] + g*u;
        }
      }
    }
  }
}

// ---------------- RoPE on q,k,v + relayout to [b*h][s][64] (bf16) -----------
__global__ __launch_bounds__(256) void rope_k(const u16* __restrict__ qkv,
    const float* __restrict__ cosb, const float* __restrict__ sinb,
    u16* __restrict__ qO, u16* __restrict__ kO, u16* __restrict__ vO)
{
  int row = blockIdx.x;
  int b = row >> 12, s = row & 4095;
  const u16* qp = qkv + (size_t)row*2304;
  for (int j = threadIdx.x; j < 576; j += 256){
    int inst = j >> 4;          // 0..35 = qkv_idx*12 + h
    int p2 = (j & 15)*2;        // d in [0,32) step 2
    int col0 = inst*64 + p2;
    float a0 = b2f(qp[col0]),     a1 = b2f(qp[col0+1]);
    float bb0 = b2f(qp[col0+32]), bb1 = b2f(qp[col0+33]);
    float c0 = cosb[s*64+p2],    c1 = cosb[s*64+p2+1];
    float c2 = cosb[s*64+p2+32], c3 = cosb[s*64+p2+33];
    float s0 = sinb[s*64+p2],    s1 = sinb[s*64+p2+1];
    float s2 = sinb[s*64+p2+32], s3 = sinb[s*64+p2+33];
    int qi = inst / 12, h = inst - qi*12;
    u16* dst = (qi == 0) ? qO : (qi == 1) ? kO : vO;
    size_t base = ((size_t)(b*12 + h)*4096 + s)*64;
    dst[base + p2]      = f2b(a0*c0 - bb0*s0);
    dst[base + p2 + 1]  = f2b(a1*c1 - bb1*s1);
    dst[base + p2 + 32] = f2b(bb0*c2 + a0*s2);
    dst[base + p2 + 33] = f2b(bb1*c3 + a1*s3);
  }
}

// ---------------- V transpose: [bh][s][64] -> [bh][64][s] -------------------
__global__ __launch_bounds__(256) void vtr_k(const u16* __restrict__ vS, u16* __restrict__ vT)
{
  __shared__ __align__(16) u16 tile[64][72];
  int st = blockIdx.x, bh = blockIdx.y;
  int t = threadIdx.x;
  #pragma unroll
  for (int i=0;i<2;i++){
    int e = i*256 + t;
    int r = e >> 3, d0 = (e & 7)*8;
    short8 vv = *(const short8*)(vS + ((size_t)bh*4096 + st*64 + r)*64 + d0);
    *(short8*)&tile[r][d0] = vv;
  }
  __syncthreads();
  #pragma unroll
  for (int i=0;i<2;i++){
    int e = i*256 + t;
    int d = e >> 3, s0 = (e & 7)*8;
    short8 ov;
    #pragma unroll
    for (int k2=0;k2<8;k2++) ov[k2] = (short)tile[s0+k2][d];
    *(short8*)(vT + ((size_t)bh*64 + d)*4096 + st*64 + s0) = ov;
  }
}

// ---------------- flash attention, 64 q-rows/block, 64-key tiles ------------
__global__ __launch_bounds__(256) void attn_k(
    const u16* __restrict__ qT, const u16* __restrict__ kT, const u16* __restrict__ vT,
    const int* __restrict__ mask, u16* __restrict__ o)
{
  __shared__ __align__(16) u16 Ks[64*64];
  __shared__ __align__(16) u16 Vs[64*64];
  __shared__ __align__(16) u16 Ps[64*64];
  const int qt = blockIdx.x, bh = blockIdx.y;
  const int b = bh / 12, h = bh - b*12;
  const int tid = threadIdx.x, w = tid >> 6, l = tid & 63;
  const int l15 = l & 15, lg = l >> 4;

  short8 aq[2];
  {
    const u16* qp = qT + ((size_t)bh*4096 + qt*64 + w*16 + l15)*64 + lg*8;
    aq[0] = *(const short8*)qp;
    aq[1] = *(const short8*)(qp + 32);
  }
  const int* mrow = mask + b*4096;
  bool fq[4];
  #pragma unroll
  for (int r=0;r<4;r++) fq[r] = mrow[qt*64 + w*16 + lg*4 + r] != 0;

  float m_run[4], l_run[4]; f32x4 oacc[4];
  #pragma unroll
  for (int r=0;r<4;r++){ m_run[r] = -1e4f; l_run[r] = 0.f; }
  #pragma unroll
  for (int n=0;n<4;n++) oacc[n] = (f32x4){0.f,0.f,0.f,0.f};

  for (int kt=0; kt<64; ++kt){
    #pragma unroll
    for (int i=0;i<2;i++){
      int e = i*256 + tid;
      int r = e >> 3, ch = e & 7;
      int sc = ch ^ (r & 7);
      gload16(kT + ((size_t)bh*4096 + kt*64 + r)*64 + sc*8, &Ks[e*8]);
      gload16(vT + ((size_t)bh*64 + r)*4096 + kt*64 + sc*8, &Vs[e*8]);
    }
    __syncthreads();

    f32x4 sf[4];
    #pragma unroll
    for (int n=0;n<4;n++){
      f32x4 acc = (f32x4){0.f,0.f,0.f,0.f};
      #pragma unroll
      for (int kk=0;kk<2;kk++){
        int rk = n*16 + l15;
        short8 bk = *(const short8*)&Ks[rk*64 + (((kk*4)+lg) ^ (rk&7))*8];
        acc = mfma16(aq[kk], bk, acc);
      }
      sf[n] = acc;
    }
    bool mk[4];
    #pragma unroll
    for (int n=0;n<4;n++) mk[n] = mrow[kt*64 + n*16 + l15] != 0;
    // Reference adds -1e9 (f32-absorbing): m_q=0 rows -> ALL scores identical
    // -> uniform softmax. Emulate: score=0 for every key. m_q=1 rows: masked
    // keys -> -1e30 (exp underflows to 0), valid keys keep score.
    #pragma unroll
    for (int n=0;n<4;n++)
      #pragma unroll
      for (int r=0;r<4;r++){
        float sv = sf[n][r]*0.125f;
        sv = fq[r] ? (mk[n] ? sv : -1e30f) : 0.f;
        sf[n][r] = sv;
      }
    float mnew[4], alpha[4], tsum[4];
    #pragma unroll
    for (int r=0;r<4;r++){
      float tm = fmaxf(fmaxf(sf[0][r], sf[1][r]), fmaxf(sf[2][r], sf[3][r]));
      #pragma unroll
      for (int d=1; d<16; d<<=1) tm = fmaxf(tm, __shfl_xor(tm, d));
      mnew[r] = fmaxf(m_run[r], tm);
      alpha[r] = __expf(m_run[r] - mnew[r]);
      tsum[r] = 0.f;
    }
    #pragma unroll
    for (int n=0;n<4;n++)
      #pragma unroll
      for (int r=0;r<4;r++){
        float p = __expf(sf[n][r] - mnew[r]);
        sf[n][r] = p;
        tsum[r] += p;
      }
    #pragma unroll
    for (int r=0;r<4;r++){
      #pragma unroll
      for (int d=1; d<16; d<<=1) tsum[r] += __shfl_xor(tsum[r], d);
      l_run[r] = l_run[r]*alpha[r] + tsum[r];
      m_run[r] = mnew[r];
    }
    #pragma unroll
    for (int n=0;n<4;n++)
      #pragma unroll
      for (int r=0;r<4;r++)
        oacc[n][r] *= alpha[r];
    // P -> LDS (own-wave stripe), same XOR swizzle
    #pragma unroll
    for (int n=0;n<4;n++)
      #pragma unroll
      for (int r=0;r<4;r++){
        int prow = w*16 + lg*4 + r;
        int col = n*16 + l15;
        int ch = col >> 3;
        Ps[prow*64 + ((ch ^ (prow&7))<<3) + (col&7)] = f2b(sf[n][r]);
      }
    __syncthreads();
    #pragma unroll
    for (int kk=0;kk<2;kk++){
      int pr = w*16 + l15;
      short8 ap = *(const short8*)&Ps[pr*64 + (((kk*4)+lg) ^ (pr&7))*8];
      #pragma unroll
      for (int n=0;n<4;n++){
        int vr = n*16 + l15;
        short8 bv = *(const short8*)&Vs[vr*64 + (((kk*4)+lg) ^ (vr&7))*8];
        oacc[n] = mfma16(ap, bv, oacc[n]);
      }
    }
    __syncthreads();
  }
  #pragma unroll
  for (int n=0;n<4;n++)
    #pragma unroll
    for (int r=0;r<4;r++){
      int row = qt*64 + w*16 + lg*4 + r;
      int col = h*64 + n*16 + l15;
      o[((size_t)b*4096 + row)*768 + col] = f2b(oacc[n][r] / l_run[r]);
    }
}

// ---------------------------------------------------------------------------
extern "C" void kernel_launch(void* const* d_in, const int* in_sizes, int n_in,
                              void* d_out, int out_size, void* d_ws, size_t ws_size,
                              hipStream_t stream)
{
  const float* x    = (const float*)d_in[0];
  const float* cosb = (const float*)d_in[1];
  const float* sinb = (const float*)d_in[2];
  const float* c    = (const float*)d_in[3];
  const int* amask  = (const int*)d_in[4];
  const float* ln1w = (const float*)d_in[5];
  const float* Wqkv = (const float*)d_in[6];
  const float* Wout = (const float*)d_in[7];
  const float* ln2w = (const float*)d_in[8];
  const float* W1   = (const float*)d_in[9];
  const float* b1   = (const float*)d_in[10];
  const float* W2   = (const float*)d_in[11];
  const float* b2   = (const float*)d_in[12];
  const float* Wada = (const float*)d_in[13];
  const float* bada = (const float*)d_in[14];

  char* ws = (char*)d_ws;
  size_t off = 0;
  auto take = [&](size_t bytes)->char*{
    char* p = ws + off; off = (off + bytes + 255) & ~(size_t)255; return p;
  };
  float* modb = (float*)take(9216*sizeof(float));
  u16* hdn  = (u16*)take((size_t)8192*768*2);    // hdn, then h2 (bf16)
  u16* bufA = (u16*)take((size_t)8192*3072*2);   // qkv raw, then MLP mid (bf16)
  u16* vS   = (u16*)take((size_t)8192*768*2);    // v (s-major)
  u16* qTb  = (u16*)take((size_t)8192*768*2);
  u16* kTb  = (u16*)take((size_t)8192*768*2);
  u16* vTb  = (u16*)take((size_t)8192*768*2);    // v (d-major)
  u16* ob   = (u16*)take((size_t)8192*768*2);    // attention output (bf16)
  u16* WqkvB= (u16*)take((size_t)2304*768*2);
  u16* WoutB= (u16*)take((size_t)768*768*2);
  u16* W1B  = (u16*)take((size_t)3072*768*2);
  u16* W2B  = (u16*)take((size_t)768*3072*2);
  float* out = (float*)d_out;
  float* x1 = out;                               // reuse d_out for x1 (f32)

  cvt_k<<<(2304*768/4+255)/256, 256, 0, stream>>>(Wqkv, WqkvB, 2304*768/4);
  cvt_k<<<(768*768/4+255)/256, 256, 0, stream>>>(Wout, WoutB, 768*768/4);
  cvt_k<<<(3072*768/4+255)/256, 256, 0, stream>>>(W1, W1B, 3072*768/4);
  cvt_k<<<(768*3072/4+255)/256, 256, 0, stream>>>(W2, W2B, 768*3072/4);

  mod_k  <<<2304, 256, 0, stream>>>(c, Wada, bada, modb);
  ln_mod_k<<<8192, 256, 0, stream>>>(x, hdn, ln1w, modb, 0, 1);
  gemm_k<0><<<dim3(64,18), 256, 0, stream>>>(hdn, WqkvB, bufA, 8192, 2304, 768,
                                             nullptr, nullptr, nullptr);
  rope_k <<<8192, 256, 0, stream>>>(bufA, cosb, sinb, qTb, kTb, vS);
  vtr_k  <<<dim3(64,24), 256, 0, stream>>>(vS, vTb);
  attn_k <<<dim3(64,24), 256, 0, stream>>>(qTb, kTb, vTb, amask, ob);
  gemm_k<1><<<dim3(64,6), 256, 0, stream>>>(ob, WoutB, x1, 8192, 768, 768,
                                            x, modb, nullptr);
  ln_mod_k<<<8192, 256, 0, stream>>>(x1, hdn, ln2w, modb, 3, 4);
  gemm_k<2><<<dim3(64,24), 256, 0, stream>>>(hdn, W1B, bufA, 8192, 3072, 768,
                                             nullptr, nullptr, b1);
  gemm_k<3><<<dim3(64,6), 256, 0, stream>>>(bufA, W2B, out, 8192, 768, 3072,
                                            x1, modb, b2);
}

// Round 5
// 452.161 us; speedup vs baseline: 1.2788x; 1.2788x over previous
//
#include <hip/hip_runtime.h>
#include <stdint.h>

// Dtype policy (confirmed): f32 I/O, bf16 MFMA internals.
// Attention v2: swapped QK^T (S^T = K·Q^T) so each lane owns ONE q-row's
// scores -> in-register softmax (2 shfl instead of 32), packed cvt_pk P
// stores into per-wave LDS stripe (no barrier), PV as O^T = V^T·P^T.
// K/V double-buffered, 1 raw barrier/iter with vmcnt(0) drain.

typedef unsigned short u16;
typedef __attribute__((ext_vector_type(4))) float f32x4;
typedef __attribute__((ext_vector_type(8))) short short8;
typedef __attribute__((ext_vector_type(4))) short s16x4;
typedef __attribute__((ext_vector_type(8))) __bf16 bf16x8;

__device__ __forceinline__ float b2f(u16 u){
  union { unsigned int i; float f; } v; v.i = ((unsigned int)u) << 16; return v.f;
}
__device__ __forceinline__ u16 f2b(float f){
  union { float f; unsigned int i; } v; v.f = f;
  unsigned int u = v.i;
  u = u + 0x7FFFu + ((u >> 16) & 1u);   // RNE
  return (u16)(u >> 16);
}
__device__ __forceinline__ f32x4 mfma16(short8 a, short8 b, f32x4 c){
  return __builtin_amdgcn_mfma_f32_16x16x32_bf16(
      __builtin_bit_cast(bf16x8, a), __builtin_bit_cast(bf16x8, b), c, 0, 0, 0);
}
__device__ __forceinline__ void gload16(const void* g, void* l){
  void* gnc = const_cast<void*>(g);
  __builtin_amdgcn_global_load_lds((__attribute__((address_space(1))) void*)gnc,
                                   (__attribute__((address_space(3))) void*)l, 16, 0, 0);
}

// ---------------- f32 -> bf16 weight conversion -----------------------------
__global__ __launch_bounds__(256) void cvt_k(const float* __restrict__ in,
                                             u16* __restrict__ out, int n4)
{
  int i = blockIdx.x*256 + threadIdx.x;
  if (i < n4){
    float4 v = *(const float4*)(in + (size_t)i*4);
    s16x4 o; o[0]=(short)f2b(v.x); o[1]=(short)f2b(v.y);
    o[2]=(short)f2b(v.z); o[3]=(short)f2b(v.w);
    *(s16x4*)(out + (size_t)i*4) = o;
  }
}

// ---------------- key-bias precompute: kbias[i] = mask? 0 : -1e30 ----------
__global__ __launch_bounds__(256) void kbias_k(const int* __restrict__ mask,
                                               float* __restrict__ kb, int n)
{
  int i = blockIdx.x*256 + threadIdx.x;
  if (i < n) kb[i] = mask[i] ? 0.f : -1e30f;
}

// ---------------- adaLN modulation: mod[b][6*768] = c @ Wada^T + bada --------
__global__ __launch_bounds__(256) void mod_k(const float* __restrict__ c,
    const float* __restrict__ Wada, const float* __restrict__ bada, float* __restrict__ modb)
{
  int o = blockIdx.x*4 + (threadIdx.x >> 6);   // 0..9215
  int l = threadIdx.x & 63;
  int b = o / 4608, j = o - b*4608;
  const float* cp = c + b*768;
  const float* wp = Wada + (size_t)j*768;
  float s = 0.f;
  for (int k = l; k < 768; k += 64) s += cp[k] * wp[k];
  #pragma unroll
  for (int d=1; d<64; d<<=1) s += __shfl_xor(s, d);
  if (l == 0) modb[o] = s + bada[j];
}

// ---------------- LayerNorm (no affine) * w * (1+scale) + shift -> bf16 -----
__global__ __launch_bounds__(256) void ln_mod_k(const float* __restrict__ xin,
    u16* __restrict__ out, const float* __restrict__ lnw, const float* __restrict__ modb,
    int shift_c, int scale_c)
{
  int row = blockIdx.x;             // 0..8191 (b*4096+s)
  int b = row >> 12;
  const float* xp = xin + (size_t)row*768;
  int t = threadIdx.x;
  float v[3]; float s = 0.f, s2 = 0.f;
  #pragma unroll
  for (int i=0;i<3;i++){ float f = xp[t + i*256]; v[i] = f; s += f; s2 += f*f; }
  #pragma unroll
  for (int d=1; d<64; d<<=1){ s += __shfl_xor(s, d); s2 += __shfl_xor(s2, d); }
  __shared__ float rs_[4], rs2_[4];
  int w = t >> 6;
  if ((t & 63) == 0){ rs_[w] = s; rs2_[w] = s2; }
  __syncthreads();
  s  = rs_[0]+rs_[1]+rs_[2]+rs_[3];
  s2 = rs2_[0]+rs2_[1]+rs2_[2]+rs2_[3];
  float mu  = s * (1.f/768.f);
  float var = fmaxf(s2 * (1.f/768.f) - mu*mu, 0.f);
  float rstd = rsqrtf(var + 1e-5f);
  const float* scp = modb + b*4608 + scale_c*768;
  const float* shp = modb + b*4608 + shift_c*768;
  #pragma unroll
  for (int i=0;i<3;i++){
    int d = t + i*256;
    float f = (v[i]-mu)*rstd*lnw[d];
    f = f*(1.f + scp[d]) + shp[d];
    out[(size_t)row*768 + d] = f2b(f);
  }
}

// ---------------- 128x128 BK=64 GEMM, C = A[M,K] @ Bt[N,K]^T, fused epilogues
// EPI 0: C(bf16)=acc (qkv).     1: C(f32) = x + gate_msa*acc (x1).
// EPI 2: C(bf16)=gelu(acc+b1).  3: C(f32) = x1 + gate_mlp*(acc+b2).
template<int EPI>
__global__ __launch_bounds__(256) void gemm_k(
    const u16* __restrict__ A, const u16* __restrict__ Bt, void* __restrict__ Cv,
    int M, int N, int K,
    const float* __restrict__ addend, const float* __restrict__ modb,
    const float* __restrict__ bias)
{
  __shared__ __align__(16) u16 As[128*64];
  __shared__ __align__(16) u16 Bs[128*64];
  const int bm = blockIdx.x, bn = blockIdx.y;
  const int tid = threadIdx.x;
  const int w = tid >> 6, l = tid & 63;
  const int wr = w >> 1, wc = w & 1;
  const int l15 = l & 15, lg = l >> 4;
  f32x4 acc[4][4] = {};

  for (int k0 = 0; k0 < K; k0 += 64){
    #pragma unroll
    for (int i=0;i<4;i++){
      int e = i*256 + tid;
      int r = e >> 3, ch = e & 7;
      int sc = ch ^ (r & 7);
      gload16(A  + (size_t)(bm*128 + r)*K + k0 + sc*8, &As[e*8]);
      gload16(Bt + (size_t)(bn*128 + r)*K + k0 + sc*8, &Bs[e*8]);
    }
    __syncthreads();
    #pragma unroll
    for (int kk=0;kk<2;kk++){
      short8 af[4], bfv[4];
      #pragma unroll
      for (int i=0;i<4;i++){
        int ra = wr*64 + i*16 + l15;
        af[i]  = *(const short8*)&As[ra*64 + (((kk*4)+lg) ^ (ra&7))*8];
        int rb = wc*64 + i*16 + l15;
        bfv[i] = *(const short8*)&Bs[rb*64 + (((kk*4)+lg) ^ (rb&7))*8];
      }
      #pragma unroll
      for (int m=0;m<4;m++)
        #pragma unroll
        for (int n=0;n<4;n++)
          acc[m][n] = mfma16(af[m], bfv[n], acc[m][n]);
    }
    __syncthreads();
  }

  #pragma unroll
  for (int m=0;m<4;m++){
    int row0 = bm*128 + wr*64 + m*16 + lg*4;
    #pragma unroll
    for (int n=0;n<4;n++){
      int col = bn*128 + wc*64 + n*16 + l15;
      #pragma unroll
      for (int r=0;r<4;r++){
        int row = row0 + r;
        size_t idx = (size_t)row*N + col;
        float v = acc[m][n][r];
        if constexpr (EPI == 0){
          ((u16*)Cv)[idx] = f2b(v);
        } else if constexpr (EPI == 1){
          float g = modb[(row>>12)*4608 + 2*768 + col];   // gate_msa
          ((float*)Cv)[idx] = addend[idx] + g*v;
        } else if constexpr (EPI == 2){
          float u = v + bias[col];
          float t0 = 0.7978845608028654f*(u + 0.044715f*u*u*u);
          ((u16*)Cv)[idx] = f2b(0.5f*u*(1.0f + tanhf(t0)));
        } else {
          float g = modb[(row>>12)*4608 + 5*768 + col];   // gate_mlp
          float u = v + bias[col];
          ((float*)Cv)[idx] = addend[idx] + g*u;
        }
      }
    }
  }
}

// ---------------- RoPE on q,k,v + relayout to [b*h][s][64] (bf16) -----------
__global__ __launch_bounds__(256) void rope_k(const u16* __restrict__ qkv,
    const float* __restrict__ cosb, const float* __restrict__ sinb,
    u16* __restrict__ qO, u16* __restrict__ kO, u16* __restrict__ vO)
{
  int row = blockIdx.x;
  int b = row >> 12, s = row & 4095;
  const u16* qp = qkv + (size_t)row*2304;
  for (int j = threadIdx.x; j < 576; j += 256){
    int inst = j >> 4;          // 0..35 = qkv_idx*12 + h
    int p2 = (j & 15)*2;        // d in [0,32) step 2
    int col0 = inst*64 + p2;
    float a0 = b2f(qp[col0]),     a1 = b2f(qp[col0+1]);
    float bb0 = b2f(qp[col0+32]), bb1 = b2f(qp[col0+33]);
    float c0 = cosb[s*64+p2],    c1 = cosb[s*64+p2+1];
    float c2 = cosb[s*64+p2+32], c3 = cosb[s*64+p2+33];
    float s0 = sinb[s*64+p2],    s1 = sinb[s*64+p2+1];
    float s2 = sinb[s*64+p2+32], s3 = sinb[s*64+p2+33];
    int qi = inst / 12, h = inst - qi*12;
    u16* dst = (qi == 0) ? qO : (qi == 1) ? kO : vO;
    size_t base = ((size_t)(b*12 + h)*4096 + s)*64;
    dst[base + p2]      = f2b(a0*c0 - bb0*s0);
    dst[base + p2 + 1]  = f2b(a1*c1 - bb1*s1);
    dst[base + p2 + 32] = f2b(bb0*c2 + a0*s2);
    dst[base + p2 + 33] = f2b(bb1*c3 + a1*s3);
  }
}

// ---------------- V transpose: [bh][s][64] -> [bh][64][s] -------------------
__global__ __launch_bounds__(256) void vtr_k(const u16* __restrict__ vS, u16* __restrict__ vT)
{
  __shared__ __align__(16) u16 tile[64][72];
  int st = blockIdx.x, bh = blockIdx.y;
  int t = threadIdx.x;
  #pragma unroll
  for (int i=0;i<2;i++){
    int e = i*256 + t;
    int r = e >> 3, d0 = (e & 7)*8;
    short8 vv = *(const short8*)(vS + ((size_t)bh*4096 + st*64 + r)*64 + d0);
    *(short8*)&tile[r][d0] = vv;
  }
  __syncthreads();
  #pragma unroll
  for (int i=0;i<2;i++){
    int e = i*256 + t;
    int d = e >> 3, s0 = (e & 7)*8;
    short8 ov;
    #pragma unroll
    for (int k2=0;k2<8;k2++) ov[k2] = (short)tile[s0+k2][d];
    *(short8*)(vT + ((size_t)bh*64 + d)*4096 + st*64 + s0) = ov;
  }
}

// ---------------- flash attention v2: swapped QK^T, in-register softmax -----
__global__ __launch_bounds__(256) void attn_k(
    const u16* __restrict__ qT, const u16* __restrict__ kT, const u16* __restrict__ vT,
    const int* __restrict__ mask, const float* __restrict__ kbias,
    u16* __restrict__ o)
{
  __shared__ __align__(16) u16 Ks[2][64*64];
  __shared__ __align__(16) u16 Vs[2][64*64];
  __shared__ __align__(16) u16 Ps[4][16*64];   // per-wave P^T stripe [q=16][s_k=64]
  const int qt = blockIdx.x, bh = blockIdx.y;
  const int b = bh / 12, h = bh - b*12;
  const int tid = threadIdx.x, w = tid >> 6, l = tid & 63;
  const int l15 = l & 15, lg = l >> 4;

  // Q fragment (B-operand of swapped QK^T): lane l15 = q-row, lg*8 = d-chunk
  short8 bq[2];
  {
    const u16* qp = qT + ((size_t)bh*4096 + qt*64 + w*16 + l15)*64 + lg*8;
    bq[0] = *(const short8*)qp;
    bq[1] = *(const short8*)(qp + 32);
  }
  const bool fq = mask[b*4096 + qt*64 + w*16 + l15] != 0;
  const float* kbrow = kbias + b*4096;

  float m_run = -1e4f, l_run = 0.f;
  f32x4 oacc[4] = {};   // O^T[d = n*16+lg*4+r][q = l15]

  // prologue: stage tile 0 into buf 0
  #pragma unroll
  for (int i=0;i<2;i++){
    int e = i*256 + tid, r = e >> 3, sc = (e&7) ^ (r&7);
    gload16(kT + ((size_t)bh*4096 + r)*64 + sc*8, &Ks[0][e*8]);
    gload16(vT + ((size_t)bh*64 + r)*4096 + sc*8, &Vs[0][e*8]);
  }
  asm volatile("s_waitcnt vmcnt(0)" ::: "memory");
  __builtin_amdgcn_s_barrier();

  for (int kt = 0; kt < 64; ++kt){
    const int buf = kt & 1;
    if (kt < 63){
      #pragma unroll
      for (int i=0;i<2;i++){
        int e = i*256 + tid, r = e >> 3, sc = (e&7) ^ (r&7);
        gload16(kT + ((size_t)bh*4096 + (kt+1)*64 + r)*64 + sc*8, &Ks[buf^1][e*8]);
        gload16(vT + ((size_t)bh*64 + r)*4096 + (kt+1)*64 + sc*8, &Vs[buf^1][e*8]);
      }
    }
    // key-bias for this tile (per lane: s_k = n*16 + lg*4 + r)
    float kb[4][4];
    #pragma unroll
    for (int n=0;n<4;n++){
      float4 kv = *(const float4*)(kbrow + kt*64 + n*16 + lg*4);
      kb[n][0]=kv.x; kb[n][1]=kv.y; kb[n][2]=kv.z; kb[n][3]=kv.w;
    }

    // S^T = K·Q^T : st[n] rows s_k = n*16+lg*4+r, col q = l15
    f32x4 st[4];
    __builtin_amdgcn_s_setprio(1);
    #pragma unroll
    for (int n=0;n<4;n++){
      int R = n*16 + l15;
      f32x4 acc = {};
      #pragma unroll
      for (int kk=0;kk<2;kk++){
        short8 ka = *(const short8*)&Ks[buf][R*64 + (((kk<<2)+lg) ^ (R&7))*8];
        acc = mfma16(ka, bq[kk], acc);
      }
      st[n] = acc;
    }
    __builtin_amdgcn_s_setprio(0);

    // scores + in-register online softmax (per-lane row q = l15)
    float p[4][4]; float pm = -1e30f;
    #pragma unroll
    for (int n=0;n<4;n++)
      #pragma unroll
      for (int r=0;r<4;r++){
        float sv = fq ? fmaf(st[n][r], 0.125f, kb[n][r]) : 0.f;
        p[n][r] = sv;
        pm = fmaxf(pm, sv);
      }
    pm = fmaxf(pm, __shfl_xor(pm, 16));
    pm = fmaxf(pm, __shfl_xor(pm, 32));
    if (pm > m_run + 8.f){          // defer-max (T13): rescale only on growth
      float al = __expf(m_run - pm);
      l_run *= al;
      #pragma unroll
      for (int n=0;n<4;n++) oacc[n] *= al;
      m_run = pm;
    }
    float ts = 0.f;
    #pragma unroll
    for (int n=0;n<4;n++)
      #pragma unroll
      for (int r=0;r<4;r++){
        float e = __expf(p[n][r] - m_run);
        p[n][r] = e; ts += e;
      }
    ts += __shfl_xor(ts, 16);
    ts += __shfl_xor(ts, 32);
    l_run += ts;

    // pack P^T -> own-wave stripe Ps[w][q=l15][s_k ^ chunk swizzle]
    #pragma unroll
    for (int n=0;n<4;n++){
      unsigned p01, p23;
      asm("v_cvt_pk_bf16_f32 %0, %1, %2" : "=v"(p01) : "v"(p[n][0]), "v"(p[n][1]));
      asm("v_cvt_pk_bf16_f32 %0, %1, %2" : "=v"(p23) : "v"(p[n][2]), "v"(p[n][3]));
      int s0 = n*16 + lg*4;
      int off = (((s0>>3) ^ (l15&7))<<3) + (s0&7);
      *(unsigned*)&Ps[w][l15*64 + off]     = p01;
      *(unsigned*)&Ps[w][l15*64 + off + 2] = p23;
    }

    // O^T += V^T · P^T   (A = Vs[d][s_k], B = Ps[s_k][q])
    __builtin_amdgcn_s_setprio(1);
    #pragma unroll
    for (int kk=0;kk<2;kk++){
      int ch = (kk<<2) + lg;
      short8 bp = *(const short8*)&Ps[w][l15*64 + ((ch ^ (l15&7))<<3)];
      #pragma unroll
      for (int n=0;n<4;n++){
        int R = n*16 + l15;
        short8 va = *(const short8*)&Vs[buf][R*64 + ((ch ^ (R&7))<<3)];
        oacc[n] = mfma16(va, bp, oacc[n]);
      }
    }
    __builtin_amdgcn_s_setprio(0);

    asm volatile("s_waitcnt vmcnt(0)" ::: "memory");
    __builtin_amdgcn_s_barrier();
  }

  float inv = 1.f / l_run;
  size_t base = ((size_t)b*4096 + qt*64 + w*16 + l15)*768 + h*64 + lg*4;
  #pragma unroll
  for (int n=0;n<4;n++){
    unsigned q01 = (unsigned)f2b(oacc[n][0]*inv) | ((unsigned)f2b(oacc[n][1]*inv) << 16);
    unsigned q23 = (unsigned)f2b(oacc[n][2]*inv) | ((unsigned)f2b(oacc[n][3]*inv) << 16);
    *(unsigned*)&o[base + n*16]     = q01;
    *(unsigned*)&o[base + n*16 + 2] = q23;
  }
}

// ---------------------------------------------------------------------------
extern "C" void kernel_launch(void* const* d_in, const int* in_sizes, int n_in,
                              void* d_out, int out_size, void* d_ws, size_t ws_size,
                              hipStream_t stream)
{
  const float* x    = (const float*)d_in[0];
  const float* cosb = (const float*)d_in[1];
  const float* sinb = (const float*)d_in[2];
  const float* c    = (const float*)d_in[3];
  const int* amask  = (const int*)d_in[4];
  const float* ln1w = (const float*)d_in[5];
  const float* Wqkv = (const float*)d_in[6];
  const float* Wout = (const float*)d_in[7];
  const float* ln2w = (const float*)d_in[8];
  const float* W1   = (const float*)d_in[9];
  const float* b1   = (const float*)d_in[10];
  const float* W2   = (const float*)d_in[11];
  const float* b2   = (const float*)d_in[12];
  const float* Wada = (const float*)d_in[13];
  const float* bada = (const float*)d_in[14];

  char* ws = (char*)d_ws;
  size_t off = 0;
  auto take = [&](size_t bytes)->char*{
    char* p = ws + off; off = (off + bytes + 255) & ~(size_t)255; return p;
  };
  float* modb = (float*)take(9216*sizeof(float));
  float* kbias= (float*)take(8192*sizeof(float));
  u16* hdn  = (u16*)take((size_t)8192*768*2);    // hdn, then h2 (bf16)
  u16* bufA = (u16*)take((size_t)8192*3072*2);   // qkv raw, then MLP mid (bf16)
  u16* vS   = (u16*)take((size_t)8192*768*2);    // v (s-major)
  u16* qTb  = (u16*)take((size_t)8192*768*2);
  u16* kTb  = (u16*)take((size_t)8192*768*2);
  u16* vTb  = (u16*)take((size_t)8192*768*2);    // v (d-major)
  u16* ob   = (u16*)take((size_t)8192*768*2);    // attention output (bf16)
  u16* WqkvB= (u16*)take((size_t)2304*768*2);
  u16* WoutB= (u16*)take((size_t)768*768*2);
  u16* W1B  = (u16*)take((size_t)3072*768*2);
  u16* W2B  = (u16*)take((size_t)768*3072*2);
  float* out = (float*)d_out;
  float* x1 = out;                               // reuse d_out for x1 (f32)

  cvt_k<<<(2304*768/4+255)/256, 256, 0, stream>>>(Wqkv, WqkvB, 2304*768/4);
  cvt_k<<<(768*768/4+255)/256, 256, 0, stream>>>(Wout, WoutB, 768*768/4);
  cvt_k<<<(3072*768/4+255)/256, 256, 0, stream>>>(W1, W1B, 3072*768/4);
  cvt_k<<<(768*3072/4+255)/256, 256, 0, stream>>>(W2, W2B, 768*3072/4);
  kbias_k<<<32, 256, 0, stream>>>(amask, kbias, 8192);

  mod_k  <<<2304, 256, 0, stream>>>(c, Wada, bada, modb);
  ln_mod_k<<<8192, 256, 0, stream>>>(x, hdn, ln1w, modb, 0, 1);
  gemm_k<0><<<dim3(64,18), 256, 0, stream>>>(hdn, WqkvB, bufA, 8192, 2304, 768,
                                             nullptr, nullptr, nullptr);
  rope_k <<<8192, 256, 0, stream>>>(bufA, cosb, sinb, qTb, kTb, vS);
  vtr_k  <<<dim3(64,24), 256, 0, stream>>>(vS, vTb);
  attn_k <<<dim3(64,24), 256, 0, stream>>>(qTb, kTb, vTb, amask, kbias, ob);
  gemm_k<1><<<dim3(64,6), 256, 0, stream>>>(ob, WoutB, x1, 8192, 768, 768,
                                            x, modb, nullptr);
  ln_mod_k<<<8192, 256, 0, stream>>>(x1, hdn, ln2w, modb, 3, 4);
  gemm_k<2><<<dim3(64,24), 256, 0, stream>>>(hdn, W1B, bufA, 8192, 3072, 768,
                                             nullptr, nullptr, b1);
  gemm_k<3><<<dim3(64,6), 256, 0, stream>>>(bufA, W2B, out, 8192, 768, 3072,
                                            x1, modb, b2);
}

// Round 6
// 434.407 us; speedup vs baseline: 1.3310x; 1.0409x over previous
//
#include <hip/hip_runtime.h>
#include <stdint.h>

// f32 I/O, bf16 MFMA internals. Attention v3: swapped QK^T (S^T = K·Q^T),
// in-register log2-domain softmax (Q pre-scaled by 0.125*log2e at RoPE),
// QBLK=128 (8 waves/block) amortizing K/V staging + barriers 2x,
// K/V double-buffered with 1 raw barrier/iter.

typedef unsigned short u16;
typedef __attribute__((ext_vector_type(4))) float f32x4;
typedef __attribute__((ext_vector_type(8))) short short8;
typedef __attribute__((ext_vector_type(4))) short s16x4;
typedef __attribute__((ext_vector_type(8))) __bf16 bf16x8;

__device__ __forceinline__ float b2f(u16 u){
  union { unsigned int i; float f; } v; v.i = ((unsigned int)u) << 16; return v.f;
}
__device__ __forceinline__ u16 f2b(float f){
  union { float f; unsigned int i; } v; v.f = f;
  unsigned int u = v.i;
  u = u + 0x7FFFu + ((u >> 16) & 1u);   // RNE
  return (u16)(u >> 16);
}
__device__ __forceinline__ f32x4 mfma16(short8 a, short8 b, f32x4 c){
  return __builtin_amdgcn_mfma_f32_16x16x32_bf16(
      __builtin_bit_cast(bf16x8, a), __builtin_bit_cast(bf16x8, b), c, 0, 0, 0);
}
__device__ __forceinline__ void gload16(const void* g, void* l){
  void* gnc = const_cast<void*>(g);
  __builtin_amdgcn_global_load_lds((__attribute__((address_space(1))) void*)gnc,
                                   (__attribute__((address_space(3))) void*)l, 16, 0, 0);
}
__device__ __forceinline__ float max3f(float a, float b, float c){
  return fmaxf(fmaxf(a, b), c);   // clang folds to v_max3_f32
}

// ---------------- f32 -> bf16 weight conversion -----------------------------
__global__ __launch_bounds__(256) void cvt_k(const float* __restrict__ in,
                                             u16* __restrict__ out, int n4)
{
  int i = blockIdx.x*256 + threadIdx.x;
  if (i < n4){
    float4 v = *(const float4*)(in + (size_t)i*4);
    s16x4 o; o[0]=(short)f2b(v.x); o[1]=(short)f2b(v.y);
    o[2]=(short)f2b(v.z); o[3]=(short)f2b(v.w);
    *(s16x4*)(out + (size_t)i*4) = o;
  }
}

// ---------------- key-bias precompute: kbias[i] = mask? 0 : -1e30 ----------
__global__ __launch_bounds__(256) void kbias_k(const int* __restrict__ mask,
                                               float* __restrict__ kb, int n)
{
  int i = blockIdx.x*256 + threadIdx.x;
  if (i < n) kb[i] = mask[i] ? 0.f : -1e30f;
}

// ---------------- adaLN modulation: mod[b][6*768] = c @ Wada^T + bada --------
__global__ __launch_bounds__(256) void mod_k(const float* __restrict__ c,
    const float* __restrict__ Wada, const float* __restrict__ bada, float* __restrict__ modb)
{
  int o = blockIdx.x*4 + (threadIdx.x >> 6);   // 0..9215
  int l = threadIdx.x & 63;
  int b = o / 4608, j = o - b*4608;
  const float* cp = c + b*768;
  const float* wp = Wada + (size_t)j*768;
  float s = 0.f;
  for (int k = l; k < 768; k += 64) s += cp[k] * wp[k];
  #pragma unroll
  for (int d=1; d<64; d<<=1) s += __shfl_xor(s, d);
  if (l == 0) modb[o] = s + bada[j];
}

// ---------------- LayerNorm (no affine) * w * (1+scale) + shift -> bf16 -----
__global__ __launch_bounds__(256) void ln_mod_k(const float* __restrict__ xin,
    u16* __restrict__ out, const float* __restrict__ lnw, const float* __restrict__ modb,
    int shift_c, int scale_c)
{
  int row = blockIdx.x;             // 0..8191 (b*4096+s)
  int b = row >> 12;
  const float* xp = xin + (size_t)row*768;
  int t = threadIdx.x;
  float v[3]; float s = 0.f, s2 = 0.f;
  #pragma unroll
  for (int i=0;i<3;i++){ float f = xp[t + i*256]; v[i] = f; s += f; s2 += f*f; }
  #pragma unroll
  for (int d=1; d<64; d<<=1){ s += __shfl_xor(s, d); s2 += __shfl_xor(s2, d); }
  __shared__ float rs_[4], rs2_[4];
  int w = t >> 6;
  if ((t & 63) == 0){ rs_[w] = s; rs2_[w] = s2; }
  __syncthreads();
  s  = rs_[0]+rs_[1]+rs_[2]+rs_[3];
  s2 = rs2_[0]+rs2_[1]+rs2_[2]+rs2_[3];
  float mu  = s * (1.f/768.f);
  float var = fmaxf(s2 * (1.f/768.f) - mu*mu, 0.f);
  float rstd = rsqrtf(var + 1e-5f);
  const float* scp = modb + b*4608 + scale_c*768;
  const float* shp = modb + b*4608 + shift_c*768;
  #pragma unroll
  for (int i=0;i<3;i++){
    int d = t + i*256;
    float f = (v[i]-mu)*rstd*lnw[d];
    f = f*(1.f + scp[d]) + shp[d];
    out[(size_t)row*768 + d] = f2b(f);
  }
}

// ---------------- 128x128 BK=64 GEMM, C = A[M,K] @ Bt[N,K]^T, fused epilogues
// EPI 0: C(bf16)=acc (qkv).     1: C(f32) = x + gate_msa*acc (x1).
// EPI 2: C(bf16)=gelu(acc+b1).  3: C(f32) = x1 + gate_mlp*(acc+b2).
template<int EPI>
__global__ __launch_bounds__(256) void gemm_k(
    const u16* __restrict__ A, const u16* __restrict__ Bt, void* __restrict__ Cv,
    int M, int N, int K,
    const float* __restrict__ addend, const float* __restrict__ modb,
    const float* __restrict__ bias)
{
  __shared__ __align__(16) u16 As[128*64];
  __shared__ __align__(16) u16 Bs[128*64];
  const int bm = blockIdx.x, bn = blockIdx.y;
  const int tid = threadIdx.x;
  const int w = tid >> 6, l = tid & 63;
  const int wr = w >> 1, wc = w & 1;
  const int l15 = l & 15, lg = l >> 4;
  f32x4 acc[4][4] = {};

  for (int k0 = 0; k0 < K; k0 += 64){
    #pragma unroll
    for (int i=0;i<4;i++){
      int e = i*256 + tid;
      int r = e >> 3, ch = e & 7;
      int sc = ch ^ (r & 7);
      gload16(A  + (size_t)(bm*128 + r)*K + k0 + sc*8, &As[e*8]);
      gload16(Bt + (size_t)(bn*128 + r)*K + k0 + sc*8, &Bs[e*8]);
    }
    __syncthreads();
    #pragma unroll
    for (int kk=0;kk<2;kk++){
      short8 af[4], bfv[4];
      #pragma unroll
      for (int i=0;i<4;i++){
        int ra = wr*64 + i*16 + l15;
        af[i]  = *(const short8*)&As[ra*64 + (((kk*4)+lg) ^ (ra&7))*8];
        int rb = wc*64 + i*16 + l15;
        bfv[i] = *(const short8*)&Bs[rb*64 + (((kk*4)+lg) ^ (rb&7))*8];
      }
      #pragma unroll
      for (int m=0;m<4;m++)
        #pragma unroll
        for (int n=0;n<4;n++)
          acc[m][n] = mfma16(af[m], bfv[n], acc[m][n]);
    }
    __syncthreads();
  }

  #pragma unroll
  for (int m=0;m<4;m++){
    int row0 = bm*128 + wr*64 + m*16 + lg*4;
    #pragma unroll
    for (int n=0;n<4;n++){
      int col = bn*128 + wc*64 + n*16 + l15;
      #pragma unroll
      for (int r=0;r<4;r++){
        int row = row0 + r;
        size_t idx = (size_t)row*N + col;
        float v = acc[m][n][r];
        if constexpr (EPI == 0){
          ((u16*)Cv)[idx] = f2b(v);
        } else if constexpr (EPI == 1){
          float g = modb[(row>>12)*4608 + 2*768 + col];   // gate_msa
          ((float*)Cv)[idx] = addend[idx] + g*v;
        } else if constexpr (EPI == 2){
          float u = v + bias[col];
          float t0 = 0.7978845608028654f*(u + 0.044715f*u*u*u);
          ((u16*)Cv)[idx] = f2b(0.5f*u*(1.0f + tanhf(t0)));
        } else {
          float g = modb[(row>>12)*4608 + 5*768 + col];   // gate_mlp
          float u = v + bias[col];
          ((float*)Cv)[idx] = addend[idx] + g*u;
        }
      }
    }
  }
}

// ---------------- RoPE on q,k,v + relayout to [b*h][s][64] (bf16) -----------
// q additionally scaled by 0.125*log2(e) so attention works in log2 domain.
__global__ __launch_bounds__(256) void rope_k(const u16* __restrict__ qkv,
    const float* __restrict__ cosb, const float* __restrict__ sinb,
    u16* __restrict__ qO, u16* __restrict__ kO, u16* __restrict__ vO)
{
  int row = blockIdx.x;
  int b = row >> 12, s = row & 4095;
  const u16* qp = qkv + (size_t)row*2304;
  for (int j = threadIdx.x; j < 576; j += 256){
    int inst = j >> 4;          // 0..35 = qkv_idx*12 + h
    int p2 = (j & 15)*2;        // d in [0,32) step 2
    int col0 = inst*64 + p2;
    float a0 = b2f(qp[col0]),     a1 = b2f(qp[col0+1]);
    float bb0 = b2f(qp[col0+32]), bb1 = b2f(qp[col0+33]);
    float c0 = cosb[s*64+p2],    c1 = cosb[s*64+p2+1];
    float c2 = cosb[s*64+p2+32], c3 = cosb[s*64+p2+33];
    float s0 = sinb[s*64+p2],    s1 = sinb[s*64+p2+1];
    float s2 = sinb[s*64+p2+32], s3 = sinb[s*64+p2+33];
    int qi = inst / 12, h = inst - qi*12;
    float qs = (qi == 0) ? 0.1803368801111601f : 1.f;  // 0.125*log2(e)
    u16* dst = (qi == 0) ? qO : (qi == 1) ? kO : vO;
    size_t base = ((size_t)(b*12 + h)*4096 + s)*64;
    dst[base + p2]      = f2b((a0*c0 - bb0*s0)*qs);
    dst[base + p2 + 1]  = f2b((a1*c1 - bb1*s1)*qs);
    dst[base + p2 + 32] = f2b((bb0*c2 + a0*s2)*qs);
    dst[base + p2 + 33] = f2b((bb1*c3 + a1*s3)*qs);
  }
}

// ---------------- V transpose: [bh][s][64] -> [bh][64][s] -------------------
__global__ __launch_bounds__(256) void vtr_k(const u16* __restrict__ vS, u16* __restrict__ vT)
{
  __shared__ __align__(16) u16 tile[64][72];
  int st = blockIdx.x, bh = blockIdx.y;
  int t = threadIdx.x;
  #pragma unroll
  for (int i=0;i<2;i++){
    int e = i*256 + t;
    int r = e >> 3, d0 = (e & 7)*8;
    short8 vv = *(const short8*)(vS + ((size_t)bh*4096 + st*64 + r)*64 + d0);
    *(short8*)&tile[r][d0] = vv;
  }
  __syncthreads();
  #pragma unroll
  for (int i=0;i<2;i++){
    int e = i*256 + t;
    int d = e >> 3, s0 = (e & 7)*8;
    short8 ov;
    #pragma unroll
    for (int k2=0;k2<8;k2++) ov[k2] = (short)tile[s0+k2][d];
    *(short8*)(vT + ((size_t)bh*64 + d)*4096 + st*64 + s0) = ov;
  }
}

// ---------------- flash attention v3: QBLK=128, 8 waves, log2 softmax -------
__global__ __launch_bounds__(512) void attn_k(
    const u16* __restrict__ qT, const u16* __restrict__ kT, const u16* __restrict__ vT,
    const int* __restrict__ mask, const float* __restrict__ kbias,
    u16* __restrict__ o)
{
  __shared__ __align__(16) u16 Ks[2][64*64];
  __shared__ __align__(16) u16 Vs[2][64*64];
  __shared__ __align__(16) u16 Ps[8][16*64];   // per-wave P^T stripe [q=16][s_k=64]
  const int qt = blockIdx.x, bh = blockIdx.y;
  const int b = bh / 12, h = bh - b*12;
  const int tid = threadIdx.x, w = tid >> 6, l = tid & 63;
  const int l15 = l & 15, lg = l >> 4;

  // Q fragment (B-operand of swapped QK^T): lane l15 = q-row, lg*8 = d-chunk
  short8 bq[2];
  {
    const u16* qp = qT + ((size_t)bh*4096 + qt*128 + w*16 + l15)*64 + lg*8;
    bq[0] = *(const short8*)qp;
    bq[1] = *(const short8*)(qp + 32);
  }
  const bool fq = mask[b*4096 + qt*128 + w*16 + l15] != 0;
  const float* kbrow = kbias + b*4096;

  float m_run = -1e4f, l_run = 0.f;
  f32x4 oacc[4] = {};   // O^T[d = n*16+lg*4+r][q = l15]

  // staging geometry: 512 threads x 16B = one full 64x64 bf16 tile per array
  const int sr = tid >> 3, ssc = (tid & 7) ^ (sr & 7);

  // prologue: stage tile 0 into buf 0
  gload16(kT + ((size_t)bh*4096 + sr)*64 + ssc*8, &Ks[0][tid*8]);
  gload16(vT + ((size_t)bh*64 + sr)*4096 + ssc*8, &Vs[0][tid*8]);
  asm volatile("s_waitcnt vmcnt(0)" ::: "memory");
  __builtin_amdgcn_s_barrier();

  for (int kt = 0; kt < 64; ++kt){
    const int buf = kt & 1;
    if (kt < 63){
      gload16(kT + ((size_t)bh*4096 + (kt+1)*64 + sr)*64 + ssc*8, &Ks[buf^1][tid*8]);
      gload16(vT + ((size_t)bh*64 + sr)*4096 + (kt+1)*64 + ssc*8, &Vs[buf^1][tid*8]);
    }
    // key-bias for this tile (per lane: s_k = n*16 + lg*4 + r)
    float kb[4][4];
    #pragma unroll
    for (int n=0;n<4;n++){
      float4 kv = *(const float4*)(kbrow + kt*64 + n*16 + lg*4);
      kb[n][0]=kv.x; kb[n][1]=kv.y; kb[n][2]=kv.z; kb[n][3]=kv.w;
    }

    // S^T = K·Q^T : st[n] rows s_k = n*16+lg*4+r, col q = l15  (log2 domain)
    f32x4 st[4];
    __builtin_amdgcn_s_setprio(1);
    #pragma unroll
    for (int n=0;n<4;n++){
      int R = n*16 + l15;
      f32x4 acc = {};
      #pragma unroll
      for (int kk=0;kk<2;kk++){
        short8 ka = *(const short8*)&Ks[buf][R*64 + (((kk<<2)+lg) ^ (R&7))*8];
        acc = mfma16(ka, bq[kk], acc);
      }
      st[n] = acc;
    }
    __builtin_amdgcn_s_setprio(0);

    // scores + in-register online softmax (per-lane row q = l15)
    float p[4][4];
    #pragma unroll
    for (int n=0;n<4;n++)
      #pragma unroll
      for (int r=0;r<4;r++)
        p[n][r] = fq ? (st[n][r] + kb[n][r]) : 0.f;
    float m0 = max3f(p[0][0], p[0][1], p[0][2]);
    float m1 = max3f(p[0][3], p[1][0], p[1][1]);
    float m2 = max3f(p[1][2], p[1][3], p[2][0]);
    float m3 = max3f(p[2][1], p[2][2], p[2][3]);
    float m4 = max3f(p[3][0], p[3][1], p[3][2]);
    float pm = fmaxf(max3f(m0, m1, m2), max3f(m3, m4, p[3][3]));
    pm = fmaxf(pm, __shfl_xor(pm, 16));
    pm = fmaxf(pm, __shfl_xor(pm, 32));
    if (__any(pm > m_run + 8.f)){   // defer-max, wave-uniform branch
      float mn = fmaxf(m_run, pm);
      float al = __builtin_amdgcn_exp2f(m_run - mn);
      l_run *= al;
      #pragma unroll
      for (int n=0;n<4;n++) oacc[n] *= al;
      m_run = mn;
    }
    float ts = 0.f;
    #pragma unroll
    for (int n=0;n<4;n++)
      #pragma unroll
      for (int r=0;r<4;r++){
        float e = __builtin_amdgcn_exp2f(p[n][r] - m_run);
        p[n][r] = e; ts += e;
      }
    ts += __shfl_xor(ts, 16);
    ts += __shfl_xor(ts, 32);
    l_run += ts;

    // pack P^T -> own-wave stripe Ps[w][q=l15][s_k ^ chunk swizzle]
    #pragma unroll
    for (int n=0;n<4;n++){
      unsigned p01, p23;
      asm("v_cvt_pk_bf16_f32 %0, %1, %2" : "=v"(p01) : "v"(p[n][0]), "v"(p[n][1]));
      asm("v_cvt_pk_bf16_f32 %0, %1, %2" : "=v"(p23) : "v"(p[n][2]), "v"(p[n][3]));
      int s0 = n*16 + lg*4;
      int off = (((s0>>3) ^ (l15&7))<<3) + (s0&7);
      *(unsigned*)&Ps[w][l15*64 + off]     = p01;
      *(unsigned*)&Ps[w][l15*64 + off + 2] = p23;
    }

    // O^T += V^T · P^T   (A = Vs[d][s_k], B = Ps[s_k][q])
    __builtin_amdgcn_s_setprio(1);
    #pragma unroll
    for (int kk=0;kk<2;kk++){
      int ch = (kk<<2) + lg;
      short8 bp = *(const short8*)&Ps[w][l15*64 + ((ch ^ (l15&7))<<3)];
      #pragma unroll
      for (int n=0;n<4;n++){
        int R = n*16 + l15;
        short8 va = *(const short8*)&Vs[buf][R*64 + ((ch ^ (R&7))<<3)];
        oacc[n] = mfma16(va, bp, oacc[n]);
      }
    }
    __builtin_amdgcn_s_setprio(0);

    asm volatile("s_waitcnt vmcnt(0)" ::: "memory");
    __builtin_amdgcn_s_barrier();
  }

  float inv = 1.f / l_run;
  size_t base = ((size_t)b*4096 + qt*128 + w*16 + l15)*768 + h*64 + lg*4;
  #pragma unroll
  for (int n=0;n<4;n++){
    unsigned q01 = (unsigned)f2b(oacc[n][0]*inv) | ((unsigned)f2b(oacc[n][1]*inv) << 16);
    unsigned q23 = (unsigned)f2b(oacc[n][2]*inv) | ((unsigned)f2b(oacc[n][3]*inv) << 16);
    *(unsigned*)&o[base + n*16]     = q01;
    *(unsigned*)&o[base + n*16 + 2] = q23;
  }
}

// ---------------------------------------------------------------------------
extern "C" void kernel_launch(void* const* d_in, const int* in_sizes, int n_in,
                              void* d_out, int out_size, void* d_ws, size_t ws_size,
                              hipStream_t stream)
{
  const float* x    = (const float*)d_in[0];
  const float* cosb = (const float*)d_in[1];
  const float* sinb = (const float*)d_in[2];
  const float* c    = (const float*)d_in[3];
  const int* amask  = (const int*)d_in[4];
  const float* ln1w = (const float*)d_in[5];
  const float* Wqkv = (const float*)d_in[6];
  const float* Wout = (const float*)d_in[7];
  const float* ln2w = (const float*)d_in[8];
  const float* W1   = (const float*)d_in[9];
  const float* b1   = (const float*)d_in[10];
  const float* W2   = (const float*)d_in[11];
  const float* b2   = (const float*)d_in[12];
  const float* Wada = (const float*)d_in[13];
  const float* bada = (const float*)d_in[14];

  char* ws = (char*)d_ws;
  size_t off = 0;
  auto take = [&](size_t bytes)->char*{
    char* p = ws + off; off = (off + bytes + 255) & ~(size_t)255; return p;
  };
  float* modb = (float*)take(9216*sizeof(float));
  float* kbias= (float*)take(8192*sizeof(float));
  u16* hdn  = (u16*)take((size_t)8192*768*2);    // hdn, then h2 (bf16)
  u16* bufA = (u16*)take((size_t)8192*3072*2);   // qkv raw, then MLP mid (bf16)
  u16* vS   = (u16*)take((size_t)8192*768*2);    // v (s-major)
  u16* qTb  = (u16*)take((size_t)8192*768*2);
  u16* kTb  = (u16*)take((size_t)8192*768*2);
  u16* vTb  = (u16*)take((size_t)8192*768*2);    // v (d-major)
  u16* ob   = (u16*)take((size_t)8192*768*2);    // attention output (bf16)
  u16* WqkvB= (u16*)take((size_t)2304*768*2);
  u16* WoutB= (u16*)take((size_t)768*768*2);
  u16* W1B  = (u16*)take((size_t)3072*768*2);
  u16* W2B  = (u16*)take((size_t)768*3072*2);
  float* out = (float*)d_out;
  float* x1 = out;                               // reuse d_out for x1 (f32)

  cvt_k<<<(2304*768/4+255)/256, 256, 0, stream>>>(Wqkv, WqkvB, 2304*768/4);
  cvt_k<<<(768*768/4+255)/256, 256, 0, stream>>>(Wout, WoutB, 768*768/4);
  cvt_k<<<(3072*768/4+255)/256, 256, 0, stream>>>(W1, W1B, 3072*768/4);
  cvt_k<<<(768*3072/4+255)/256, 256, 0, stream>>>(W2, W2B, 768*3072/4);
  kbias_k<<<32, 256, 0, stream>>>(amask, kbias, 8192);

  mod_k  <<<2304, 256, 0, stream>>>(c, Wada, bada, modb);
  ln_mod_k<<<8192, 256, 0, stream>>>(x, hdn, ln1w, modb, 0, 1);
  gemm_k<0><<<dim3(64,18), 256, 0, stream>>>(hdn, WqkvB, bufA, 8192, 2304, 768,
                                             nullptr, nullptr, nullptr);
  rope_k <<<8192, 256, 0, stream>>>(bufA, cosb, sinb, qTb, kTb, vS);
  vtr_k  <<<dim3(64,24), 256, 0, stream>>>(vS, vTb);
  attn_k <<<dim3(32,24), 512, 0, stream>>>(qTb, kTb, vTb, amask, kbias, ob);
  gemm_k<1><<<dim3(64,6), 256, 0, stream>>>(ob, WoutB, x1, 8192, 768, 768,
                                            x, modb, nullptr);
  ln_mod_k<<<8192, 256, 0, stream>>>(x1, hdn, ln2w, modb, 3, 4);
  gemm_k<2><<<dim3(64,24), 256, 0, stream>>>(hdn, W1B, bufA, 8192, 3072, 768,
                                             nullptr, nullptr, b1);
  gemm_k<3><<<dim3(64,6), 256, 0, stream>>>(bufA, W2B, out, 8192, 768, 3072,
                                            x1, modb, b2);
}